// Round 4
// baseline (2475.101 us; speedup 1.0000x reference)
//
#include <hip/hip_runtime.h>
#include <hip/hip_bf16.h>

// Bidirectional LSTM, B=256, S=256, E=300, H=512.
// Persistent cooperative scan: 256 WGs = 2 dir x 4 batch-tiles(64) x 32 j-tiles(16 h-cols).
// TRANSPOSED MFMA: D = W' x h^T via mfma_f32_32x32x16_bf16; A = W' (LDS-resident, gate-in-row&3
// ordering -> each lane holds all 4 gates of its outputs, zero shuffles), B = h/xe from global.
// Sync: per-(WG,wave) flags, waves fully decoupled (no __syncthreads in the scan loop).
// h-exchange via XCD-local L2 (plain stores + sc0 loads) when the group is XCD-homogeneous
// (verified at runtime via HW_REG_XCC_ID + one-time grid barrier); else IF$ (sc0 sc1) fallback.

#define SQ 256
#define NB 256
#define HD 512
#define ED 300
#define EP 320
#define KW 832   // 512 + 320
#define G4 2048

typedef __attribute__((ext_vector_type(8))) short bf16x8;
typedef __attribute__((ext_vector_type(16))) float f32x16;
typedef __attribute__((ext_vector_type(4))) int i32x4;

#define MFMA32 __builtin_amdgcn_mfma_f32_32x32x16_bf16

__device__ __forceinline__ unsigned short f2bf(float x) {
  union { float f; unsigned u; } v; v.f = x;
  unsigned r = v.u + 0x7FFFu + ((v.u >> 16) & 1u);
  return (unsigned short)(r >> 16);
}
__device__ __forceinline__ float sigf(float x) { return 1.f / (1.f + __expf(-x)); }
__device__ __forceinline__ float tanhf_(float x) {
  float t = __expf(-2.f * fabsf(x));
  float r = (1.f - t) / (1.f + t);
  return x < 0.f ? -r : r;
}

__global__ void k_zero(unsigned* __restrict__ p, int n) {
  int i = blockIdx.x * 256 + threadIdx.x;
  if (i < n) p[i] = 0u;
}

// W' bf16 [2][2048][832] = [W_hh | W_ih | 0-pad] per gate row
__global__ void k_prep_w(const float* __restrict__ Wihf, const float* __restrict__ Whhf,
                         const float* __restrict__ Wihb, const float* __restrict__ Whhb,
                         unsigned short* __restrict__ Wp) {
  int idx = blockIdx.x * 256 + threadIdx.x;
  if (idx >= 2 * G4 * KW) return;
  int d = idx / (G4 * KW);
  int rem = idx % (G4 * KW);
  int R = rem / KW, k = rem % KW;
  const float* Whh = d ? Whhb : Whhf;
  const float* Wih = d ? Wihb : Wihf;
  float v = 0.f;
  if (k < HD) v = Whh[R * HD + k];
  else if (k < HD + ED) v = Wih[R * ED + (k - HD)];
  Wp[idx] = f2bf(v);
}

// xe bf16 [S][B][320] = emb[tok] padded
__global__ void k_prep_xe(const int* __restrict__ x, const float* __restrict__ emb,
                          unsigned short* __restrict__ xe) {
  const int bidx = blockIdx.x;           // t*NB + b
  const int t = bidx / NB, b = bidx % NB;
  const int tok = x[b * SQ + t];         // x is (B,1,S)
  unsigned short* dst = xe + (size_t)(t * NB + b) * EP;
  const float* src = emb + (size_t)tok * ED;
  for (int e = threadIdx.x; e < EP; e += 64)
    dst[e] = (e < ED) ? f2bf(src[e]) : (unsigned short)0;
}

// ---- global-load helpers (FAST: XCD-local L2; SLOW: IF$-coherent) ----
template<bool FAST, int OFF>
__device__ __forceinline__ i32x4 ldg16(const unsigned short* p) {
  i32x4 r;
  if constexpr (FAST)
    asm volatile("global_load_dwordx4 %0, %1, off offset:%2 sc0"
                 : "=v"(r) : "v"(p), "i"(OFF));
  else
    asm volatile("global_load_dwordx4 %0, %1, off offset:%2 sc0 sc1"
                 : "=v"(r) : "v"(p), "i"(OFF));
  return r;
}
template<bool FAST, int OFF>
__device__ __forceinline__ void st2(unsigned short* p, unsigned v) {
  if constexpr (FAST)
    asm volatile("global_store_short %0, %1, off offset:%2"
                 :: "v"(p), "v"(v), "i"(OFF) : "memory");
  else
    asm volatile("global_store_short %0, %1, off offset:%2 sc0 sc1"
                 :: "v"(p), "v"(v), "i"(OFF) : "memory");
}

template<bool FAST>
__device__ void scan_body(const unsigned short* __restrict__ xe,
                          const float* __restrict__ bias,
                          unsigned short* __restrict__ hbuf,
                          float* __restrict__ hfin,
                          unsigned* __restrict__ flg) {
  extern __shared__ unsigned short wlds[];   // [2 mq][52 cc][64 lane][8] bf16 = 106496 B
  const int p = blockIdx.x;
  const int g8 = p & 7;
  const int d  = g8 >> 2;
  const int bg = g8 & 3;
  const int ct = p >> 3;
  const int tid = threadIdx.x;
  const int lane = tid & 63;
  const int wv = tid >> 6;
  const int mq = wv >> 1, nq = wv & 1;
  const int hi = lane >> 5, l31 = lane & 31;
  const int kh = hi << 3;

  const int b = bg * 64 + nq * 32 + l31;       // batch col this lane owns
  const int jbase = ct * 16 + mq * 8 + hi;     // j of outputs: jbase + 2u

  float br[16];
  #pragma unroll
  for (int r = 0; r < 16; ++r)
    br[r] = bias[(r & 3) * HD + jbase + 2 * (r >> 2)];

  const unsigned short* wH = wlds + (mq * 52) * 512 + lane * 8;   // h chunks cc=0..31
  const unsigned short* wX = wH + 32 * 512;                        // xe chunks cc=32..51
  const unsigned* fp = flg + (g8 << 7) + lane;
  unsigned* fmine = flg + (g8 << 7) + ct * 4 + wv;

  float cst[4] = {0.f, 0.f, 0.f, 0.f};

  for (int t = 0; t < SQ; ++t) {
    const int tx = d ? (SQ - 1 - t) : t;
    f32x16 acc;
    #pragma unroll
    for (int r = 0; r < 16; ++r) acc[r] = br[r];

    // ---- xe phase (K 512..831): h-independent, before the poll ----
    const unsigned short* xb = xe + ((size_t)tx * NB + b) * EP + kh;
    #pragma unroll
    for (int cx = 0; cx < 20; ++cx) {
      bf16x8 bb = *(const bf16x8*)(xb + cx * 16);
      bf16x8 aa = *(const bf16x8*)(wX + cx * 512);
      acc = MFMA32(aa, bb, acc, 0, 0, 0);
    }

    if (t > 0) {
      // ---- per-wave poll of 128 (WG,wave) flags; no intra-WG sync ----
      const unsigned tgt = (unsigned)t;
      while (1) {
        unsigned v0, v1;
        asm volatile("global_load_dword %0, %2, off sc0 sc1\n\t"
                     "global_load_dword %1, %2, off offset:256 sc0 sc1\n\t"
                     "s_waitcnt vmcnt(0)"
                     : "=&v"(v0), "=&v"(v1) : "v"(fp) : "memory");
        if (__all((int)((v0 >= tgt) & (v1 >= tgt)))) break;
        __builtin_amdgcn_s_sleep(1);
      }

      // ---- h phase (K 0..511), double-buffered counted-vmcnt loads ----
      const unsigned short* hb =
          hbuf + ((size_t)((t & 1) * 2 + d) * NB + b) * HD + kh;
      i32x4 bufA[8], bufB[8];
      #pragma unroll
      for (int j = 0; j < 8; ++j) bufA[j] = ldg16<FAST, 0>(hb + j * 16);
      #pragma unroll
      for (int blk = 0; blk < 4; ++blk) {
        i32x4* cur = (blk & 1) ? bufB : bufA;
        i32x4* nxt = (blk & 1) ? bufA : bufB;
        if (blk < 3) {
          #pragma unroll
          for (int j = 0; j < 8; ++j)
            nxt[j] = ldg16<FAST, 0>(hb + ((blk + 1) * 8 + j) * 16);
          asm volatile("s_waitcnt vmcnt(8)");
        } else {
          asm volatile("s_waitcnt vmcnt(0)");
        }
        __builtin_amdgcn_sched_barrier(0);
        #pragma unroll
        for (int j = 0; j < 8; ++j) {
          bf16x8 aa = *(const bf16x8*)(wH + (blk * 8 + j) * 512);
          acc = MFMA32(aa, __builtin_bit_cast(bf16x8, cur[j]), acc, 0, 0, 0);
        }
      }
    }

    // ---- epilogue: all 4 gates local per lane; c in regs ----
    unsigned short* hout =
        hbuf + ((size_t)(((t & 1) ^ 1) * 2 + d) * NB + b) * HD + jbase;
    #pragma unroll
    for (int u = 0; u < 4; ++u) {
      const float I = sigf(acc[4 * u + 0]);
      const float F = sigf(acc[4 * u + 1]);
      const float G = tanhf_(acc[4 * u + 2]);
      const float O = sigf(acc[4 * u + 3]);
      const float c = F * cst[u] + I * G;
      cst[u] = c;
      const float h = O * tanhf_(c);
      if (t == SQ - 1) {
        hfin[((size_t)d * NB + b) * HD + jbase + 2 * u] = h;
      } else {
        const unsigned hv = f2bf(h);
        if (u == 0) st2<FAST, 0>(hout, hv);
        if (u == 1) st2<FAST, 4>(hout, hv);
        if (u == 2) st2<FAST, 8>(hout, hv);
        if (u == 3) st2<FAST, 12>(hout, hv);
      }
    }

    if (t < SQ - 1) {
      asm volatile("s_waitcnt vmcnt(0)" ::: "memory");   // per-wave store drain
      if (lane == 0) {
        unsigned fv = (unsigned)(t + 1);
        asm volatile("global_store_dword %0, %1, off sc0 sc1"
                     :: "v"(fmine), "v"(fv) : "memory");
      }
    }
  }
}

__global__ __launch_bounds__(256, 1) void lstm_scan(
    const unsigned short* __restrict__ Wp,    // [2][2048][832] bf16
    const unsigned short* __restrict__ xe,    // [S][B][320] bf16
    const float* __restrict__ bias_f,
    const float* __restrict__ bias_b,
    unsigned short* __restrict__ hbuf,        // [2 parity][2 dir][B][H] bf16
    float* __restrict__ hfin,                 // [2][B][H] f32
    unsigned* __restrict__ flg,               // [8][128]
    unsigned* __restrict__ xcdm,              // [8]
    unsigned* __restrict__ gbar)              // [1]
{
  extern __shared__ unsigned short wlds[];
  __shared__ unsigned s_mask;
  const int p = blockIdx.x;
  const int g8 = p & 7;
  const int d  = g8 >> 2;
  const int ct = p >> 3;
  const int tid = threadIdx.x;

  // announce my XCD early
  unsigned xcc;
  asm volatile("s_getreg_b32 %0, hwreg(HW_REG_XCC_ID)" : "=s"(xcc));
  if (tid == 0) {
    __hip_atomic_fetch_or(&xcdm[g8], 1u << (xcc & 31),
                          __ATOMIC_RELEASE, __HIP_MEMORY_SCOPE_AGENT);
    __hip_atomic_fetch_add(gbar, 1u, __ATOMIC_ACQ_REL, __HIP_MEMORY_SCOPE_AGENT);
  }

  // stage W' into LDS: slot (m, cc, l) -> A-row rho=l&31: gate=rho&3, j'=rho>>2
  {
    for (int u = tid; u < 2 * 52 * 64; u += 256) {
      const int m = u / (52 * 64);
      const int rem = u % (52 * 64);
      const int cc = rem >> 6, l = rem & 63;
      const int rho = l & 31;
      const int R = (rho & 3) * HD + ct * 16 + m * 8 + (rho >> 2);
      const int k = cc * 16 + (l >> 5) * 8;
      bf16x8 v = *(const bf16x8*)(Wp + ((size_t)d * G4 + R) * KW + k);
      *(bf16x8*)&wlds[u * 8] = v;
    }
  }

  // one-time DIY grid barrier, then read the group's XCD mask
  if (tid == 0) {
    while (1) {
      unsigned g;
      asm volatile("global_load_dword %0, %1, off sc0 sc1\n\ts_waitcnt vmcnt(0)"
                   : "=v"(g) : "v"(gbar) : "memory");
      if (g >= 256u) break;
      __builtin_amdgcn_s_sleep(8);
    }
    unsigned mk;
    asm volatile("global_load_dword %0, %1, off sc0 sc1\n\ts_waitcnt vmcnt(0)"
                 : "=v"(mk) : "v"(&xcdm[g8]) : "memory");
    s_mask = mk;
  }
  __syncthreads();

  const float* bias = d ? bias_b : bias_f;
  if (__popc(s_mask) == 1)
    scan_body<true>(xe, bias, hbuf, hfin, flg);
  else
    scan_body<false>(xe, bias, hbuf, hfin, flg);
}

__global__ void k_out(const float* __restrict__ hfin, const float* __restrict__ Wo,
                      const float* __restrict__ bo, float* __restrict__ out) {
  const int b = blockIdx.x;
  const int tid = threadIdx.x;
  float s = 0.f;
  for (int k = tid; k < 1024; k += 256)
    s += hfin[((k >> 9) * NB + b) * HD + (k & 511)] * Wo[k];
  #pragma unroll
  for (int o = 32; o > 0; o >>= 1) s += __shfl_down(s, o, 64);
  __shared__ float red[4];
  if ((tid & 63) == 0) red[tid >> 6] = s;
  __syncthreads();
  if (tid == 0) out[b] = red[0] + red[1] + red[2] + red[3] + bo[0];
}

extern "C" void kernel_launch(void* const* d_in, const int* in_sizes, int n_in,
                              void* d_out, int out_size, void* d_ws, size_t ws_size,
                              hipStream_t stream) {
  const int*   x    = (const int*)d_in[0];
  const float* emb  = (const float*)d_in[1];
  const float* Wihf = (const float*)d_in[2];
  const float* Whhf = (const float*)d_in[3];
  const float* bf   = (const float*)d_in[4];
  const float* Wihb = (const float*)d_in[5];
  const float* Whhb = (const float*)d_in[6];
  const float* bb   = (const float*)d_in[7];
  const float* Wo   = (const float*)d_in[8];
  const float* bo   = (const float*)d_in[9];
  float* out = (float*)d_out;

  // ws layout:
  //   Wp   @ 0          : 6,815,744
  //   xe   @ 6,815,744  : 41,943,040
  //   hbuf @ 48,758,784 : 1,048,576
  //   flg  @ 49,807,360 : 4,096
  //   xcdm @ 49,811,456 : 32
  //   gbar @ 49,811,488 : 16
  //   hfin @ 49,811,504 : 1,048,576   (ends 50,860,080)
  char* ws = (char*)d_ws;
  unsigned short* Wp   = (unsigned short*)(ws + 0);
  unsigned short* xe   = (unsigned short*)(ws + 6815744);
  unsigned short* hbuf = (unsigned short*)(ws + 48758784);
  unsigned*       flg  = (unsigned*)(ws + 49807360);
  unsigned*       xcdm = (unsigned*)(ws + 49811456);
  unsigned*       gbar = (unsigned*)(ws + 49811488);
  float*          hfin = (float*)(ws + 49811504);

  // zero hbuf + flg + xcdm + gbar (48,758,784 .. 49,811,504 = 263,180 words)
  k_zero<<<1029, 256, 0, stream>>>((unsigned*)(ws + 48758784), 263180);
  k_prep_w<<<(2 * G4 * KW + 255) / 256, 256, 0, stream>>>(Wihf, Whhf, Wihb, Whhb, Wp);
  k_prep_xe<<<SQ * NB, 64, 0, stream>>>(x, emb, xe);

  const int ldsBytes = 2 * 52 * 64 * 8 * 2;  // 106,496
  hipFuncSetAttribute((const void*)lstm_scan,
                      hipFuncAttributeMaxDynamicSharedMemorySize, ldsBytes);

  void* args[] = { (void*)&Wp, (void*)&xe, (void*)&bf, (void*)&bb,
                   (void*)&hbuf, (void*)&hfin, (void*)&flg,
                   (void*)&xcdm, (void*)&gbar };
  hipLaunchCooperativeKernel((const void*)lstm_scan, dim3(256), dim3(256), args,
                             ldsBytes, stream);

  k_out<<<NB, 256, 0, stream>>>(hfin, Wo, bo, out);
}

// Round 9
// 2472.286 us; speedup vs baseline: 1.0011x; 1.0011x over previous
//
#include <hip/hip_runtime.h>
#include <hip/hip_bf16.h>

// Bidirectional LSTM, B=256, S=256, E=300, H=512.
// Persistent scan: 256 WGs = 2 dir x 4 batch-tiles(64) x 32 j-tiles(16 h-cols).
// D = W' x h^T via mfma_f32_32x32x16_bf16. A (W') h-part in VGPRs (128 regs), xe-part in LDS.
// h and xe in B-fragment-native layout [k-slot][b][8] -> recurring loads/stores coalesced.
// h-exchange + flags via relaxed SYSTEM-scope __hip_atomic_load/store (cache-bypassing, at IF$).
// Producer ordering: h-stores -> __threadfence_block() (vmcnt drain, NO L2 maintenance) -> flag.
// ROUND 9: replace hipLaunchCooperativeKernel with a PLAIN <<<256,256>>> launch.
// Rounds 5-8's bit-identical failure = out[b] ~= b_out => hfin never written => the coop launch
// silently rejected the high-VGPR kernel (rounds 3-4, VGPR~80, launched; rounds 5-8, ~360+, did not).
// No grid_sync is used anywhere; with grid=256 <= 256 CUs x occupancy>=1 all WGs are resident by
// capacity, so the flag-spin protocol is deadlock-free under a normal launch.

#define SQ 256
#define NB 256
#define HD 512
#define ED 300
#define KW 832   // 512 + 320
#define G4 2048

typedef __attribute__((ext_vector_type(8))) short bf16x8;
typedef __attribute__((ext_vector_type(16))) float f32x16;
typedef unsigned long long u64;

#define MFMA32 __builtin_amdgcn_mfma_f32_32x32x16_bf16

__device__ __forceinline__ unsigned short f2bf(float x) {
  union { float f; unsigned u; } v; v.f = x;
  unsigned r = v.u + 0x7FFFu + ((v.u >> 16) & 1u);
  return (unsigned short)(r >> 16);
}
__device__ __forceinline__ float sigf(float x) { return 1.f / (1.f + __expf(-x)); }
__device__ __forceinline__ float tanhf_(float x) {
  float t = __expf(-2.f * fabsf(x));
  float r = (1.f - t) / (1.f + t);
  return x < 0.f ? -r : r;
}

__global__ void k_zero(unsigned* __restrict__ p, int n) {
  int i = blockIdx.x * 256 + threadIdx.x;
  if (i < n) p[i] = 0u;
}

// W' bf16 [2][2048][832] = [W_hh | W_ih | 0-pad] per gate row
__global__ void k_prep_w(const float* __restrict__ Wihf, const float* __restrict__ Whhf,
                         const float* __restrict__ Wihb, const float* __restrict__ Whhb,
                         unsigned short* __restrict__ Wp) {
  int idx = blockIdx.x * 256 + threadIdx.x;
  if (idx >= 2 * G4 * KW) return;
  int d = idx / (G4 * KW);
  int rem = idx % (G4 * KW);
  int R = rem / KW, k = rem % KW;
  const float* Whh = d ? Whhb : Whhf;
  const float* Wih = d ? Wihb : Wihf;
  float v = 0.f;
  if (k < HD) v = Whh[R * HD + k];
  else if (k < HD + ED) v = Wih[R * ED + (k - HD)];
  Wp[idx] = f2bf(v);
}

// xeT bf16 [S][20 cx][2 hi][256 b][8] : fragment-native emb[tok] (k = cx*16 + hi*8 + e)
__global__ void k_prep_xe2(const int* __restrict__ x, const float* __restrict__ emb,
                           unsigned short* __restrict__ xeT) {
  const int t = blockIdx.x >> 2, qq = blockIdx.x & 3;
  __shared__ int tok[NB];
  if (threadIdx.x < NB) tok[threadIdx.x] = x[threadIdx.x * SQ + t];
  __syncthreads();
  unsigned short* dst = xeT + (size_t)t * 81920;
  const int u0 = qq * 20480;
  for (int u = u0 + threadIdx.x; u < u0 + 20480; u += 256) {
    const int e = u & 7, b = (u >> 3) & 255, hi = (u >> 11) & 1, cx = u >> 12;
    const int k = cx * 16 + hi * 8 + e;
    float v = (k < ED) ? emb[(size_t)tok[b] * ED + k] : 0.f;
    dst[u] = f2bf(v);
  }
}

__global__ __launch_bounds__(256, 1) void lstm_scan(
    const unsigned short* __restrict__ Wp,    // [2][2048][832] bf16
    const unsigned short* __restrict__ xeT,   // [S][20][2][256][8] bf16
    const float* __restrict__ bias_f,
    const float* __restrict__ bias_b,
    unsigned short* __restrict__ hbufT,       // [2 par][2 d][64 slot][256 b][8] bf16
    float* __restrict__ hfin,                 // [2][B][H] f32
    unsigned* __restrict__ flg) {             // [8 groups][128]
  __shared__ unsigned short wldsX[20480];     // [2 mq][20 cx][64 lane][8] = 40 KiB
  const int p = blockIdx.x;
  const int g8 = p & 7, d = g8 >> 2, bg = g8 & 3, ct = p >> 3;
  const int tid = threadIdx.x, lane = tid & 63, wv = tid >> 6;
  const int mq = wv >> 1, nq = wv & 1;
  const int hi = lane >> 5, l31 = lane & 31;
  const int b = bg * 64 + nq * 32 + l31;
  const int jbase = ct * 16 + mq * 8 + hi;

  // stage xe-phase A fragments into LDS
  for (int u = tid; u < 2560; u += 256) {
    const int m = u / 1280, rem = u % 1280;
    const int cx = rem >> 6, l = rem & 63;
    const int rho = l & 31, hiw = l >> 5;
    const int R = (rho & 3) * HD + ct * 16 + m * 8 + (rho >> 2);
    const int k = 512 + cx * 16 + hiw * 8;
    bf16x8 v = *(const bf16x8*)(Wp + ((size_t)d * G4 + R) * KW + k);
    *(bf16x8*)&wldsX[(size_t)u * 8] = v;
  }
  __syncthreads();

  // h-phase A fragments -> registers (32 x bf16x8 = 128 VGPR)
  bf16x8 ha[32];
  {
    const int R = (l31 & 3) * HD + ct * 16 + mq * 8 + (l31 >> 2);
    const unsigned short* wr = Wp + ((size_t)d * G4 + R) * KW + hi * 8;
    #pragma unroll
    for (int cc = 0; cc < 32; ++cc) ha[cc] = *(const bf16x8*)(wr + cc * 16);
  }
  const float* bias = d ? bias_b : bias_f;
  float br[16];
  #pragma unroll
  for (int r = 0; r < 16; ++r)
    br[r] = bias[(r & 3) * HD + jbase + 2 * (r >> 2)];

  unsigned* fpoll = flg + (g8 << 7) + lane;
  unsigned* fmine = flg + (g8 << 7) + ct * 4 + wv;
  const unsigned short* wx = wldsX + ((size_t)mq * 1280 + lane) * 8;
  float cst[4] = {0.f, 0.f, 0.f, 0.f};

  for (int t = 0; t < SQ; ++t) {
    const int tx = d ? (SQ - 1 - t) : t;
    f32x16 a0, a1, a2, a3;
    #pragma unroll
    for (int r = 0; r < 16; ++r) { a0[r] = br[r]; a1[r] = 0.f; a2[r] = 0.f; a3[r] = 0.f; }

    // ---- xe phase (k 512..831): h-independent, before the poll ----
    const unsigned short* xb = xeT + (size_t)tx * 81920 + ((size_t)hi * 256 + b) * 8;
    #pragma unroll
    for (int cx = 0; cx < 20; ++cx) {
      bf16x8 bbv = *(const bf16x8*)(xb + cx * 4096);
      bf16x8 aav = *(const bf16x8*)(wx + cx * 512);
      switch (cx & 3) {
        case 0: a0 = MFMA32(aav, bbv, a0, 0, 0, 0); break;
        case 1: a1 = MFMA32(aav, bbv, a1, 0, 0, 0); break;
        case 2: a2 = MFMA32(aav, bbv, a2, 0, 0, 0); break;
        case 3: a3 = MFMA32(aav, bbv, a3, 0, 0, 0); break;
      }
    }

    if (t > 0) {
      // ---- per-wave poll of all 128 (WG,wave) flags; relaxed system atomics ----
      const unsigned tgt = (unsigned)t;
      while (1) {
        unsigned v0 = __hip_atomic_load(fpoll, __ATOMIC_RELAXED, __HIP_MEMORY_SCOPE_SYSTEM);
        unsigned v1 = __hip_atomic_load(fpoll + 64, __ATOMIC_RELAXED, __HIP_MEMORY_SCOPE_SYSTEM);
        if (__all((int)((v0 >= tgt) & (v1 >= tgt)))) break;
        __builtin_amdgcn_s_sleep(1);
      }

      // ---- h phase (k 0..511): coalesced cache-bypassing fragment loads ----
      const u64* hb64 = (const u64*)(hbufT + (size_t)((t & 1) * 2 + d) * 131072 +
                                     ((size_t)hi * 256 + b) * 8);
      bf16x8 hbv[32];
      #pragma unroll
      for (int j = 0; j < 32; ++j) {
        u64 lo = __hip_atomic_load(hb64 + (size_t)j * 1024,
                                   __ATOMIC_RELAXED, __HIP_MEMORY_SCOPE_SYSTEM);
        u64 hh = __hip_atomic_load(hb64 + (size_t)j * 1024 + 1,
                                   __ATOMIC_RELAXED, __HIP_MEMORY_SCOPE_SYSTEM);
        union { u64 q[2]; bf16x8 v; } U;
        U.q[0] = lo; U.q[1] = hh;
        hbv[j] = U.v;
      }
      #pragma unroll
      for (int j = 0; j < 32; ++j) {
        switch (j & 3) {
          case 0: a0 = MFMA32(ha[j], hbv[j], a0, 0, 0, 0); break;
          case 1: a1 = MFMA32(ha[j], hbv[j], a1, 0, 0, 0); break;
          case 2: a2 = MFMA32(ha[j], hbv[j], a2, 0, 0, 0); break;
          case 3: a3 = MFMA32(ha[j], hbv[j], a3, 0, 0, 0); break;
        }
      }
    }

    // ---- epilogue: all 4 gates local per lane; c in regs ----
    f32x16 ac;
    #pragma unroll
    for (int r = 0; r < 16; ++r) ac[r] = (a0[r] + a1[r]) + (a2[r] + a3[r]);
    float hv[4];
    #pragma unroll
    for (int u = 0; u < 4; ++u) {
      const float I = sigf(ac[4 * u + 0]);
      const float F = sigf(ac[4 * u + 1]);
      const float G = tanhf_(ac[4 * u + 2]);
      const float O = sigf(ac[4 * u + 3]);
      const float c = F * cst[u] + I * G;
      cst[u] = c;
      hv[u] = O * tanhf_(c);
    }
    if (t == SQ - 1) {
      #pragma unroll
      for (int u = 0; u < 4; ++u)
        hfin[((size_t)d * NB + b) * HD + jbase + 2 * u] = hv[u];
    } else {
      // pack: slot s=ct*2+mq, batch b, 8 shorts [e] = h[s*8+e]; e = hi + 2u interleave.
      // lane(hi) assembles the 8-byte half it can: hi=0 -> e0..3, hi=1 -> e4..7.
      const unsigned d0 = (unsigned)f2bf(hv[0]) | ((unsigned)f2bf(hv[1]) << 16);
      const unsigned d1 = (unsigned)f2bf(hv[2]) | ((unsigned)f2bf(hv[3]) << 16);
      const unsigned pd0 = (unsigned)__shfl_xor((int)d0, 32, 64);
      const unsigned pd1 = (unsigned)__shfl_xor((int)d1, 32, 64);
      const unsigned A = hi ? pd1 : d0;   // even-position pair source
      const unsigned B = hi ? d1 : pd0;   // odd-position pair source
      const u64 w = (u64)(A & 0xFFFFu) | ((u64)(B & 0xFFFFu) << 16) |
                    ((u64)(A >> 16) << 32) | ((u64)(B >> 16) << 48);
      u64* hout = (u64*)(hbufT + (size_t)(((t & 1) ^ 1) * 2 + d) * 131072 +
                         ((size_t)(ct * 2 + mq) * 256 + b) * 8 + hi * 4);
      __hip_atomic_store(hout, w, __ATOMIC_RELAXED, __HIP_MEMORY_SCOPE_SYSTEM);
      __threadfence_block();   // vmcnt drain: h-stores acked at coherence point
      if (lane == 0)
        __hip_atomic_store(fmine, (unsigned)(t + 1),
                           __ATOMIC_RELAXED, __HIP_MEMORY_SCOPE_SYSTEM);
    }
  }
}

__global__ void k_out(const float* __restrict__ hfin, const float* __restrict__ Wo,
                      const float* __restrict__ bo, float* __restrict__ out) {
  const int b = blockIdx.x;
  const int tid = threadIdx.x;
  float s = 0.f;
  for (int k = tid; k < 1024; k += 256)
    s += hfin[((k >> 9) * NB + b) * HD + (k & 511)] * Wo[k];
  #pragma unroll
  for (int o = 32; o > 0; o >>= 1) s += __shfl_down(s, o, 64);
  __shared__ float red[4];
  if ((tid & 63) == 0) red[tid >> 6] = s;
  __syncthreads();
  if (tid == 0) out[b] = red[0] + red[1] + red[2] + red[3] + bo[0];
}

extern "C" void kernel_launch(void* const* d_in, const int* in_sizes, int n_in,
                              void* d_out, int out_size, void* d_ws, size_t ws_size,
                              hipStream_t stream) {
  const int*   x    = (const int*)d_in[0];
  const float* emb  = (const float*)d_in[1];
  const float* Wihf = (const float*)d_in[2];
  const float* Whhf = (const float*)d_in[3];
  const float* bf   = (const float*)d_in[4];
  const float* Wihb = (const float*)d_in[5];
  const float* Whhb = (const float*)d_in[6];
  const float* bb   = (const float*)d_in[7];
  const float* Wo   = (const float*)d_in[8];
  const float* bo   = (const float*)d_in[9];
  float* out = (float*)d_out;

  // ws layout:
  //   Wp    @ 0          : 6,815,744
  //   xeT   @ 6,815,744  : 41,943,040
  //   hbufT @ 48,758,784 : 1,048,576
  //   flg   @ 49,807,360 : 4,096
  //   hfin  @ 49,811,456 : 1,048,576
  char* ws = (char*)d_ws;
  unsigned short* Wp    = (unsigned short*)(ws + 0);
  unsigned short* xeT   = (unsigned short*)(ws + 6815744);
  unsigned short* hbufT = (unsigned short*)(ws + 48758784);
  unsigned*       flg   = (unsigned*)(ws + 49807360);
  float*          hfin  = (float*)(ws + 49811456);

  // zero hbufT + flg (1,052,672 B = 263,168 words)
  k_zero<<<1028, 256, 0, stream>>>((unsigned*)(ws + 48758784), 263168);
  k_prep_w<<<(2 * G4 * KW + 255) / 256, 256, 0, stream>>>(Wihf, Whhf, Wihb, Whhb, Wp);
  k_prep_xe2<<<SQ * 4, 256, 0, stream>>>(x, emb, xeT);

  // PLAIN launch (no cooperative API). grid=256 <= 256 CUs x occupancy(>=1): all WGs resident.
  lstm_scan<<<dim3(256), dim3(256), 0, stream>>>(Wp, xeT, bf, bb, hbufT, hfin, flg);

  k_out<<<NB, 256, 0, stream>>>(hfin, Wo, bo, out);
}